// Round 14
// baseline (673.158 us; speedup 1.0000x reference)
//
#include <hip/hip_runtime.h>
#include <math.h>

typedef __attribute__((ext_vector_type(4))) float f32x4;
typedef __attribute__((ext_vector_type(8))) short bf16x8;
typedef __attribute__((ext_vector_type(4))) unsigned short u16x4;
typedef __attribute__((ext_vector_type(8))) unsigned short u16x8;

__device__ __forceinline__ unsigned short f2bf(float f) {
  unsigned u = __builtin_bit_cast(unsigned, f);
  u += 0x7fffu + ((u >> 16) & 1u);
  return (unsigned short)(u >> 16);
}
__device__ __forceinline__ float bf2f(unsigned short s) {
  return __builtin_bit_cast(float, (unsigned)s << 16);
}
__device__ __forceinline__ float sigmoidf_(float x) { return 1.f / (1.f + __expf(-x)); }

// ---------------------------------------------------------------------------
// Batched fp32 -> bf16 conversion. Each job converted in 2048-elem blocks.
// ---------------------------------------------------------------------------
struct CJob { const float* s; unsigned short* d; int nblk; };
struct CJobs { CJob j[14]; };

__global__ __launch_bounds__(256) void conv_k(CJobs jb) {
  int b = blockIdx.x;
  int i = 0;
  while (b >= jb.j[i].nblk) { b -= jb.j[i].nblk; ++i; }
  const long base = (long)b * 2048 + threadIdx.x * 8;
  f32x4 a = *(const f32x4*)(jb.j[i].s + base);
  f32x4 c = *(const f32x4*)(jb.j[i].s + base + 4);
  u16x8 o;
  o[0] = f2bf(a[0]); o[1] = f2bf(a[1]); o[2] = f2bf(a[2]); o[3] = f2bf(a[3]);
  o[4] = f2bf(c[0]); o[5] = f2bf(c[1]); o[6] = f2bf(c[2]); o[7] = f2bf(c[3]);
  *(u16x8*)(jb.j[i].d + base) = o;
}

// ---------------------------------------------------------------------------
// gemm2_k: all-bf16 A/B, 128xTN tile, BK=32, single-buffered LDS staged via
// global_load_lds width=16 (m97 structure: 2 barriers/K-step, no staging
// VGPRs). Thread t stages 16B at LDS row t>>2, seg (t&3)*8 -> within a wave
// the LDS dest is base + lane*16 (HW requirement). Epilogues as gemm_k.
// ---------------------------------------------------------------------------
template <int TN, int ACAT, int BCAT, int EPI, int OBF16>
__global__ __launch_bounds__(256) void gemm2_k(
    const unsigned short* __restrict__ A1, const unsigned short* __restrict__ A1b,
    int lda1, long aZ,
    const unsigned short* __restrict__ A2, int lda2, int Ksplit,
    const unsigned short* __restrict__ B1, const unsigned short* __restrict__ B1b,
    int ldb1, long bZ,
    const unsigned short* __restrict__ B2, int ldb2,
    const float* __restrict__ bias1, const float* __restrict__ bias1b, long biasZ,
    const float* __restrict__ bias2,
    void* __restrict__ C, void* __restrict__ Cb, int ldc, long cZ,
    int K, int zs, float scale,
    const float* __restrict__ P0, const float* __restrict__ P1,
    const float* __restrict__ P2, const float* __restrict__ P3) {
  constexpr int NBI = TN / 32;
  __shared__ unsigned short As[128][32];
  __shared__ unsigned short Bs[TN][32];
  const int t = threadIdx.x;
  const int lane = t & 63;
  const int wave = t >> 6;
  const int wr = wave >> 1, wc = wave & 1;

  const unsigned gx = gridDim.x, gy = gridDim.y;
  unsigned L = blockIdx.x + gx * (blockIdx.y + gy * blockIdx.z);
  const unsigned nwg = gx * gy * gridDim.z;
  L = (L & 7u) * (nwg >> 3) + (L >> 3);
  const int bn = L % gx;
  const unsigned r1 = L / gx;
  const int bm = r1 % gy;
  const int z = r1 / gy;

  const bool hi = z >= zs;
  const int zz = hi ? z - zs : z;
  const unsigned short* Abase = (hi ? A1b : A1) + (long)zz * aZ;
  const unsigned short* Bbase = (hi ? B1b : B1) + (long)zz * bZ;
  const float* biasp = hi ? bias1b : bias1;
  char* Czc = (char*)(hi ? Cb : C) + (long)zz * cZ * (OBF16 ? 2 : 4);

  const int rowT = t >> 2;        // 0..63
  const int segT = (t & 3) * 8;   // bf16 elem offset (16B)

  const int kIters = K >> 5;
  f32x4 acc[4][NBI] = {};
  for (int kt = 0; kt < kIters; ++kt) {
    const int k0 = kt << 5;
    const unsigned short* Ap; int ldA, kA;
    if (ACAT == 1 && k0 >= Ksplit) { Ap = A2; ldA = lda2; kA = k0 - Ksplit; }
    else { Ap = Abase; ldA = lda1; kA = k0; }
    const unsigned short* Bp; int ldB, kB;
    if (BCAT == 1 && k0 >= Ksplit) { Bp = B2; ldB = ldb2; kB = k0 - Ksplit; }
    else { Bp = Bbase; ldB = ldb1; kB = k0; }

    __syncthreads();  // previous compute done -> LDS free
#pragma unroll
    for (int i = 0; i < 2; ++i) {
      const unsigned short* g = Ap + ((long)bm * 128 + rowT + 64 * i) * ldA + kA + segT;
      __builtin_amdgcn_global_load_lds(
          (const __attribute__((address_space(1))) void*)g,
          (__attribute__((address_space(3))) void*)&As[rowT + 64 * i][segT], 16, 0, 0);
    }
#pragma unroll
    for (int i = 0; i < TN / 64; ++i) {
      const unsigned short* g = Bp + ((long)bn * TN + rowT + 64 * i) * ldB + kB + segT;
      __builtin_amdgcn_global_load_lds(
          (const __attribute__((address_space(1))) void*)g,
          (__attribute__((address_space(3))) void*)&Bs[rowT + 64 * i][segT], 16, 0, 0);
    }
    __syncthreads();  // barrier drains vmcnt -> tile staged

    bf16x8 af[4], bfr[NBI];
#pragma unroll
    for (int mi = 0; mi < 4; ++mi)
      af[mi] = *(const bf16x8*)&As[wr * 64 + mi * 16 + (lane & 15)][(lane >> 4) * 8];
#pragma unroll
    for (int ni = 0; ni < NBI; ++ni)
      bfr[ni] = *(const bf16x8*)&Bs[wc * (TN / 2) + ni * 16 + (lane & 15)][(lane >> 4) * 8];
#pragma unroll
    for (int mi = 0; mi < 4; ++mi)
#pragma unroll
      for (int ni = 0; ni < NBI; ++ni)
        acc[mi][ni] = __builtin_amdgcn_mfma_f32_16x16x32_bf16(af[mi], bfr[ni], acc[mi][ni], 0, 0, 0);
  }

  const int colb = bn * TN + wc * (TN / 2);
  const int rowb = bm * 128 + wr * 64;
#pragma unroll
  for (int mi = 0; mi < 4; ++mi) {
#pragma unroll
    for (int ni = 0; ni < NBI; ++ni) {
      f32x4 v = acc[mi][ni];
      const int col = colb + ni * 16 + (lane & 15);
      const int row0 = rowb + mi * 16 + ((lane >> 4) << 2);
      float bsum = 0.f;
      if (biasp) bsum += biasp[zz * biasZ + col];
      if (bias2) bsum += bias2[col];
#pragma unroll
      for (int q = 0; q < 4; ++q) {
        const long row = row0 + q;
        const long off = row * ldc + col;
        const float val = v[q] + bsum;
        if (EPI == 0) {
          if (OBF16) ((unsigned short*)Czc)[off] = f2bf(val * scale);
          else       ((float*)Czc)[off] = val * scale;
        } else if (EPI == 2) {
          const float g = sigmoidf_(val);
          const float ce = P0[row * 256 + (col & 255)];
          const float ex = P1[off];
          ((float*)Czc)[off] = (P2[off] + P3[off] + ce + g * (ex - ce)) * (1.f / 3.f);
        } else if (EPI == 3) {
          ((unsigned short*)Czc)[off] = f2bf(val * P0[2 * row + (hi ? 1 : 0)]);
        } else if (EPI == 4) {
          ((float*)Czc)[off] = val + P2[2 * row] * P0[col] + P2[2 * row + 1] * P1[col];
        }
      }
    }
  }
}

// ---------------------------------------------------------------------------
// Legacy gemm_k (register-staged) — retained for the f32-A small GEMMs.
// ABF16/BBF16: operand dtype. EPI 0/1 used here.
// EPI 1: val+P0+P1 (f32 C; if Cb, also bf16 mirror to Cb)
// ---------------------------------------------------------------------------
template <int TN, int EPI, int ABF16, int BBF16, int OBF16>
__global__ __launch_bounds__(256) void gemm_k(
    const void* __restrict__ A1, int lda1,
    const void* __restrict__ B1, int ldb1,
    const float* __restrict__ bias1,
    void* __restrict__ C, void* __restrict__ Cb, int ldc,
    int K, float scale,
    const float* __restrict__ P0, const float* __restrict__ P1) {
  constexpr int NBI = TN / 32;
  __shared__ unsigned short As[2][128][32];
  __shared__ unsigned short Bs[2][TN][32];
  const int t = threadIdx.x;
  const int lane = t & 63;
  const int wave = t >> 6;
  const int wr = wave >> 1, wc = wave & 1;

  const unsigned gx = gridDim.x, gy = gridDim.y;
  unsigned L = blockIdx.x + gx * blockIdx.y;
  const unsigned nwg = gx * gy;
  L = (L & 7u) * (nwg >> 3) + (L >> 3);
  const int bn = L % gx;
  const int bm = L / gx;

  const int ar = t >> 3;
  const int bc = (t & 7) * 4;

  const int kIters = K >> 5;
  u16x4 Ra[4], Rb[NBI];

  auto loadT = [&](int kt) {
    const int k0 = kt << 5;
#pragma unroll
    for (int i = 0; i < 4; ++i) {
      const long aoff = ((long)bm * 128 + ar + 32 * i) * lda1 + k0 + bc;
      if (ABF16) {
        Ra[i] = *(const u16x4*)((const unsigned short*)A1 + aoff);
      } else {
        f32x4 v = *(const f32x4*)((const float*)A1 + aoff);
        u16x4 pk;
        pk[0] = f2bf(v[0]); pk[1] = f2bf(v[1]); pk[2] = f2bf(v[2]); pk[3] = f2bf(v[3]);
        Ra[i] = pk;
      }
    }
#pragma unroll
    for (int i = 0; i < NBI; ++i) {
      const long boff = ((long)bn * TN + ar + 32 * i) * ldb1 + k0 + bc;
      if (BBF16) {
        Rb[i] = *(const u16x4*)((const unsigned short*)B1 + boff);
      } else {
        f32x4 bv = *(const f32x4*)((const float*)B1 + boff);
        u16x4 bp;
        bp[0] = f2bf(bv[0]); bp[1] = f2bf(bv[1]); bp[2] = f2bf(bv[2]); bp[3] = f2bf(bv[3]);
        Rb[i] = bp;
      }
    }
  };

  loadT(0);

  f32x4 acc[4][NBI] = {};
  int p = 0;
  for (int kt = 0; kt < kIters; ++kt) {
    __syncthreads();
#pragma unroll
    for (int i = 0; i < 4; ++i) *(u16x4*)&As[p][ar + 32 * i][bc] = Ra[i];
#pragma unroll
    for (int i = 0; i < NBI; ++i) *(u16x4*)&Bs[p][ar + 32 * i][bc] = Rb[i];
    if (kt + 1 < kIters) loadT(kt + 1);
    __syncthreads();

    bf16x8 af[4], bfr[NBI];
#pragma unroll
    for (int mi = 0; mi < 4; ++mi)
      af[mi] = *(const bf16x8*)&As[p][wr * 64 + mi * 16 + (lane & 15)][(lane >> 4) * 8];
#pragma unroll
    for (int ni = 0; ni < NBI; ++ni)
      bfr[ni] = *(const bf16x8*)&Bs[p][wc * (TN / 2) + ni * 16 + (lane & 15)][(lane >> 4) * 8];
#pragma unroll
    for (int mi = 0; mi < 4; ++mi)
#pragma unroll
      for (int ni = 0; ni < NBI; ++ni)
        acc[mi][ni] = __builtin_amdgcn_mfma_f32_16x16x32_bf16(af[mi], bfr[ni], acc[mi][ni], 0, 0, 0);
    p ^= 1;
  }

  const int colb = bn * TN + wc * (TN / 2);
  const int rowb = bm * 128 + wr * 64;
#pragma unroll
  for (int mi = 0; mi < 4; ++mi) {
#pragma unroll
    for (int ni = 0; ni < NBI; ++ni) {
      f32x4 v = acc[mi][ni];
      const int col = colb + ni * 16 + (lane & 15);
      const int row0 = rowb + mi * 16 + ((lane >> 4) << 2);
      float bsum = 0.f;
      if (bias1) bsum += bias1[col];
#pragma unroll
      for (int q = 0; q < 4; ++q) {
        const long row = row0 + q;
        const long off = row * ldc + col;
        const float val = v[q] + bsum;
        if (EPI == 0) {
          if (OBF16) ((unsigned short*)C)[off] = f2bf(val * scale);
          else       ((float*)C)[off] = val * scale;
        } else {  // EPI 1
          const float r2 = val + P0[off] + P1[off];
          ((float*)C)[off] = r2;
          if (Cb) ((unsigned short*)Cb)[off] = f2bf(r2);
        }
      }
    }
  }
}

// 64x64 LDS-tiled transpose, f32 in -> bf16 out. out[n][d] = bf16(in[d][n])
__global__ __launch_bounds__(256) void transpose_k(const float* __restrict__ in0,
                                                   unsigned short* __restrict__ out0,
                                                   const float* __restrict__ in1,
                                                   unsigned short* __restrict__ out1, int n) {
  __shared__ float tile[64][65];
  const float* in = blockIdx.z ? in1 : in0;
  unsigned short* out = blockIdx.z ? out1 : out0;
  const int tr = blockIdx.y, tc = blockIdx.x, t = threadIdx.x;
#pragma unroll
  for (int it = 0; it < 16; ++it) {
    int idx = t + 256 * it;
    int r = idx >> 6, c = idx & 63;
    tile[r][c] = in[(long)(tr * 64 + r) * n + tc * 64 + c];
  }
  __syncthreads();
#pragma unroll
  for (int it = 0; it < 16; ++it) {
    int idx = t + 256 * it;
    int rr = idx >> 6, cc = idx & 63;
    out[(long)(tc * 64 + rr) * n + tr * 64 + cc] = f2bf(tile[cc][rr]);
  }
}

// LSTM elementwise + fused router; emits hl in f32 (ws+out) and bf16 (hlb)
__global__ __launch_bounds__(256) void lstm_k(const float* __restrict__ gates,
                                              const float* __restrict__ c_in,
                                              const float* __restrict__ Wr,
                                              const float* __restrict__ br,
                                              float* __restrict__ c_out,
                                              float* __restrict__ h_ws,
                                              float* __restrict__ h_out,
                                              unsigned short* __restrict__ hlb,
                                              float* __restrict__ rw) {
  const int b = blockIdx.x, t = threadIdx.x;
  const long base = (long)b * 1024 + t * 4;
  const float* gb = gates + (long)b * 4096 + t * 4;
  f32x4 gi = *(const f32x4*)(gb);
  f32x4 gf = *(const f32x4*)(gb + 1024);
  f32x4 gg = *(const f32x4*)(gb + 2048);
  f32x4 go = *(const f32x4*)(gb + 3072);
  f32x4 cv = *(const f32x4*)(c_in + base);
  f32x4 cn, hv;
#pragma unroll
  for (int q = 0; q < 4; ++q) {
    float cc = sigmoidf_(gf[q]) * cv[q] + sigmoidf_(gi[q]) * tanhf(gg[q]);
    cn[q] = cc;
    hv[q] = sigmoidf_(go[q]) * tanhf(cc);
  }
  *(f32x4*)(c_out + base) = cn;
  *(f32x4*)(h_ws + base) = hv;
  *(f32x4*)(h_out + base) = hv;
  u16x4 hp;
  hp[0] = f2bf(hv[0]); hp[1] = f2bf(hv[1]); hp[2] = f2bf(hv[2]); hp[3] = f2bf(hv[3]);
  *(u16x4*)(hlb + base) = hp;
  f32x4 w0 = *(const f32x4*)(Wr + t * 4);
  f32x4 w1 = *(const f32x4*)(Wr + 1024 + t * 4);
  float a0 = hv[0] * w0[0] + hv[1] * w0[1] + hv[2] * w0[2] + hv[3] * w0[3];
  float a1 = hv[0] * w1[0] + hv[1] * w1[1] + hv[2] * w1[2] + hv[3] * w1[3];
#pragma unroll
  for (int m = 32; m >= 1; m >>= 1) {
    a0 += __shfl_xor(a0, m);
    a1 += __shfl_xor(a1, m);
  }
  __shared__ float red[8];
  if ((t & 63) == 0) { red[t >> 6] = a0; red[4 + (t >> 6)] = a1; }
  __syncthreads();
  if (t == 0) {
    float z0 = red[0] + red[1] + red[2] + red[3] + br[0];
    float z1 = red[4] + red[5] + red[6] + red[7] + br[1];
    float mx = fmaxf(z0, z1);
    float e0 = __expf(z0 - mx), e1 = __expf(z1 - mx);
    float s = e0 + e1;
    rw[2 * b] = e0 / s;
    rw[2 * b + 1] = e1 / s;
  }
}

// ---------------------------------------------------------------------------
// FUSED attention (unchanged from round 13): scores + softmax + ts + V-mix.
// ---------------------------------------------------------------------------
__global__ __launch_bounds__(256) void attn10_k(
    const float* __restrict__ memK, const float* __restrict__ memV,
    const float* __restrict__ extK, const float* __restrict__ extV,
    const float* __restrict__ hl,
    const unsigned short* __restrict__ qtS, const unsigned short* __restrict__ qtE,
    unsigned short* __restrict__ mixS, unsigned short* __restrict__ mixE,
    float* __restrict__ ts) {
  const int NB = 2048, H = 1024;
  __shared__ float qtf[256 * 36];
  __shared__ float S_lds[32][8];
  __shared__ float P_lds[256];
  unsigned flat = blockIdx.x + gridDim.x * blockIdx.y;
  flat = (flat & 7u) * 512u + (flat >> 3);
  const int b = flat & 2047;
  const bool self = (flat >> 11) == 0;
  const int t = threadIdx.x;

  {
    const unsigned short* qtb = (self ? qtS : qtE) + (long)b * 8192;
#pragma unroll
    for (int i = 0; i < 4; ++i) {
      const int chunk = t + 256 * i;
      const int hh = chunk >> 7;
      const int pos = (chunk & 127) * 8;
      u16x8 qv = *(const u16x8*)(qtb + hh * 1024 + pos);
      const int kq0 = pos >> 2;
      f32x4 a, bb;
      a[0] = bf2f(qv[0]); a[1] = bf2f(qv[1]); a[2] = bf2f(qv[2]); a[3] = bf2f(qv[3]);
      bb[0] = bf2f(qv[4]); bb[1] = bf2f(qv[5]); bb[2] = bf2f(qv[6]); bb[3] = bf2f(qv[7]);
      *(f32x4*)&qtf[kq0 * 36 + hh * 4] = a;
      *(f32x4*)&qtf[(kq0 + 1) * 36 + hh * 4] = bb;
    }
  }
  __syncthreads();

  const int r = t >> 3, sub = t & 7;
  const float* Kr = self ? ((r < 31) ? memK + ((long)(r + 1) * NB + b) * H : hl + (long)b * H)
                         : extK + ((long)r * NB + b) * H;
  float acc[8] = {};
#pragma unroll
  for (int i = 0; i < 32; i += 4) {
    f32x4 kv[4];
#pragma unroll
    for (int u = 0; u < 4; ++u) kv[u] = *(const f32x4*)(Kr + ((i + u) * 8 + sub) * 4);
#pragma unroll
    for (int u = 0; u < 4; ++u) {
      const float* qp = &qtf[((i + u) * 8 + sub) * 36];
#pragma unroll
      for (int hh = 0; hh < 8; ++hh) {
        f32x4 q = *(const f32x4*)(qp + hh * 4);
        acc[hh] += kv[u][0] * q[0] + kv[u][1] * q[1] + kv[u][2] * q[2] + kv[u][3] * q[3];
      }
    }
  }
#pragma unroll
  for (int hh = 0; hh < 8; ++hh) {
    acc[hh] += __shfl_xor(acc[hh], 1);
    acc[hh] += __shfl_xor(acc[hh], 2);
    acc[hh] += __shfl_xor(acc[hh], 4);
  }
  if (sub == 0) {
#pragma unroll
    for (int hh = 0; hh < 8; ++hh) S_lds[r][hh] = acc[hh];
  }
  __syncthreads();

  {
    const int l = t & 31, hh = t >> 5;
    float Sv = S_lds[l][hh];
    float mx = Sv;
#pragma unroll
    for (int m = 16; m >= 1; m >>= 1) mx = fmaxf(mx, __shfl_xor(mx, m, 32));
    float pr = __expf(Sv - mx);
    float su = pr;
#pragma unroll
    for (int m = 16; m >= 1; m >>= 1) su += __shfl_xor(su, m, 32);
    P_lds[l * 8 + hh] = pr / su;
  }

  if (self) {
    const float* Kb = memK + (long)b * H + 4 * t;
    f32x4 a = {};
#pragma unroll
    for (int l = 0; l < 31; ++l) a += *(const f32x4*)(Kb + (long)(l + 1) * NB * H);
    a += *(const f32x4*)(hl + (long)b * H + 4 * t);
    *(f32x4*)(ts + (long)b * H + 4 * t) = a * (1.f / 32.f);
  }
  __syncthreads();

  const float* Vbase = (self ? memV + (long)NB * H : extV) + (long)b * H + 4 * t;
  const float* hlp = hl + (long)b * H + 4 * t;
  f32x4 vacc[8] = {};
#pragma unroll
  for (int l = 0; l < 32; l += 2) {
    f32x4 vv0 = *(const f32x4*)(Vbase + (long)l * NB * H);
    f32x4 vv1 = *(const f32x4*)((self && l + 1 == 31) ? hlp
                                                      : Vbase + (long)(l + 1) * NB * H);
    const float* Pl0 = &P_lds[l * 8];
    const float* Pl1 = &P_lds[(l + 1) * 8];
#pragma unroll
    for (int hh = 0; hh < 8; ++hh) vacc[hh] += Pl0[hh] * vv0;
#pragma unroll
    for (int hh = 0; hh < 8; ++hh) vacc[hh] += Pl1[hh] * vv1;
  }
  unsigned short* mixp = (self ? mixS : mixE) + (long)b * 8192;
#pragma unroll
  for (int hh = 0; hh < 8; ++hh) {
    u16x4 pk;
    pk[0] = f2bf(vacc[hh][0]); pk[1] = f2bf(vacc[hh][1]);
    pk[2] = f2bf(vacc[hh][2]); pk[3] = f2bf(vacc[hh][3]);
    *(u16x4*)(mixp + hh * 1024 + 4 * t) = pk;
  }
}

extern "C" void kernel_launch(void* const* d_in, const int* in_sizes, int n_in,
                              void* d_out, int out_size, void* d_ws, size_t ws_size,
                              hipStream_t stream) {
  const float* x    = (const float*)d_in[0];
  const float* h    = (const float*)d_in[1];
  const float* c    = (const float*)d_in[2];
  const float* memK = (const float*)d_in[3];
  const float* memV = (const float*)d_in[4];
  const float* extK = (const float*)d_in[5];
  const float* extV = (const float*)d_in[6];
  const float* W_ih = (const float*)d_in[7];
  const float* W_hh = (const float*)d_in[8];
  const float* b_ih = (const float*)d_in[9];
  const float* b_hh = (const float*)d_in[10];
  const float* sWq = (const float*)d_in[11];
  const float* sbq = (const float*)d_in[12];
  const float* sWk = (const float*)d_in[13];
  const float* sWv = (const float*)d_in[15];
  const float* sbv = (const float*)d_in[16];
  const float* sWo = (const float*)d_in[17];
  const float* sbo = (const float*)d_in[18];
  const float* cWq = (const float*)d_in[19];
  const float* cbq = (const float*)d_in[20];
  const float* cWk = (const float*)d_in[21];
  const float* cWv = (const float*)d_in[23];
  const float* cbv = (const float*)d_in[24];
  const float* cWo = (const float*)d_in[25];
  const float* cbo = (const float*)d_in[26];
  const float* Wres = (const float*)d_in[27];
  const float* bres = (const float*)d_in[28];
  const float* Wrout = (const float*)d_in[29];
  const float* brout = (const float*)d_in[30];
  const float* Wcomp = (const float*)d_in[31];
  const float* bcomp = (const float*)d_in[32];
  const float* Wexp = (const float*)d_in[33];
  const float* bexp = (const float*)d_in[34];
  const float* Wgate = (const float*)d_in[35];
  const float* bgate = (const float*)d_in[36];
  (void)in_sizes; (void)n_in; (void)out_size; (void)ws_size;

  float* out = (float*)d_out;
  float* w = (float*)d_ws;
  const long M1 = 1024 * 1024;
  const long U = 1024 * 1024;
  unsigned short* ub = (unsigned short*)w;

  float* gates   = w;            // [2048,4096] f32 ; dead after lstm_k
  float* hl      = w + 8 * M1;
  unsigned short* qsS = (unsigned short*)(w + 10 * M1);
  unsigned short* qsE = (unsigned short*)(w + 12 * M1);
  unsigned short* qtS = (unsigned short*)(w + 16 * M1);
  unsigned short* qtE = (unsigned short*)(w + 32 * M1);
  unsigned short* mixS = (unsigned short*)(w + 48 * M1);
  unsigned short* mixE = (unsigned short*)(w + 64 * M1);
  float* ts      = w + 80 * M1;
  unsigned short* attnS = (unsigned short*)(w + 82 * M1);
  unsigned short* attnE = (unsigned short*)(w + 84 * M1);
  float* rw      = w + 90 * M1;
  float* rattn   = w + 91 * M1;
  float* routed  = w + 93 * M1;
  float* comp    = w + 95 * M1;
  float* expd    = w + 96 * M1;

  unsigned short* Wihb  = ub + 48 * U;
  unsigned short* Whhb  = ub + 52 * U;
  unsigned short* xb    = ub + 56 * U;
  unsigned short* hb    = ub + 58 * U;
  unsigned short* sWqb  = ub + 60 * U;
  unsigned short* cWqb  = ub + 61 * U;
  unsigned short* sWvb  = ub + 62 * U;
  unsigned short* cWvb  = ub + 63 * U;
  unsigned short* sWob  = ub + 80 * U;
  unsigned short* cWob  = ub + 81 * U;
  unsigned short* Wresb = ub + 82 * U;
  unsigned short* Wcompb= ub + 83 * U;
  unsigned short* Wexpb = ub + 84 * U;
  unsigned short* Wgateb= ub + 85 * U;
  unsigned short* wkTsb = ub + 87 * U;
  unsigned short* wkTcb = ub + 88 * U;
  unsigned short* hlb   = ub + 89 * U;
  unsigned short* routedb = ub + 91 * U;

  float* hFinal_out = out;
  float* hl_out     = out + 2 * M1;
  float* cn_out     = out + 4 * M1;

  const float scaleq = 0.08838834764831845f;
  const int ZBIG = 1 << 30;
  dim3 blk(256);
  const float* nf = nullptr;
  const unsigned short* nu = nullptr;

  CJobs jb;
  jb.j[0] = {x, xb, 1024};
  jb.j[1] = {h, hb, 1024};
  jb.j[2] = {W_ih, Wihb, 2048};
  jb.j[3] = {W_hh, Whhb, 2048};
  jb.j[4] = {sWq, sWqb, 512};
  jb.j[5] = {cWq, cWqb, 512};
  jb.j[6] = {sWv, sWvb, 512};
  jb.j[7] = {cWv, cWvb, 512};
  jb.j[8] = {sWo, sWob, 512};
  jb.j[9] = {cWo, cWob, 512};
  jb.j[10] = {Wres, Wresb, 512};
  jb.j[11] = {Wcomp, Wcompb, 128};
  jb.j[12] = {Wexp, Wexpb, 128};
  jb.j[13] = {Wgate, Wgateb, 1024};
  conv_k<<<11008, blk, 0, stream>>>(jb);

  transpose_k<<<dim3(16, 16, 2), blk, 0, stream>>>(sWk, wkTsb, cWk, wkTcb, 1024);

  // gates = x@W_ih^T + h@W_hh^T + b_ih + b_hh  (gload_lds GEMM)
  gemm2_k<128, 1, 1, 0, 0><<<dim3(32, 16, 1), blk, 0, stream>>>(
      xb, nu, 1024, 0, hb, 1024, 1024,
      Wihb, nu, 1024, 0, Whhb, 1024,
      b_ih, nf, 0, b_hh,
      gates, nullptr, 4096, 0,
      2048, ZBIG, 1.f, nf, nf, nf, nf);

  lstm_k<<<2048, blk, 0, stream>>>(gates, c, Wrout, brout, cn_out, hl, hl_out, hlb, rw);

  // qs (z=0 self, z=1 ext), scaled, bf16 out
  gemm2_k<128, 0, 0, 0, 1><<<dim3(8, 16, 2), blk, 0, stream>>>(
      hlb, hlb, 1024, 0, nu, 0, 0,
      sWqb, cWqb, 1024, 0, nu, 0,
      sbq, cbq, 0, nf,
      qsS, qsE, 1024, 0,
      1024, 1, scaleq, nf, nf, nf, nf);

  // qt = qs @ wkT ; z: 0-7 self, 8-15 ext
  gemm2_k<128, 0, 0, 0, 1><<<dim3(8, 16, 16), blk, 0, stream>>>(
      qsS, qsE, 1024, 128, nu, 0, 0,
      wkTsb, wkTcb, 1024, 128, nu, 0,
      nf, nf, 0, nf,
      qtS, qtE, 8192, 1024,
      128, 8, 1.f, nf, nf, nf, nf);

  // fused attention (scores + softmax + ts + V-mix)
  attn10_k<<<dim3(2048, 2), blk, 0, stream>>>(memK, memV, extK, extV, hl,
                                              qtS, qtE, mixS, mixE, ts);

  // attn' = (mix@Wv_h^T + bv) * rw
  gemm2_k<64, 0, 0, 3, 1><<<dim3(2, 16, 16), blk, 0, stream>>>(
      mixS, mixE, 8192, 1024, nu, 0, 0,
      sWvb, cWvb, 1024, 131072, nu, 0,
      sbv, cbv, 128, nf,
      attnS, attnE, 1024, 128,
      1024, 8, 1.f, rw, nf, nf, nf);

  // rattn = [w0*attnS | w1*attnE] @ [sWo;cWo]^T + w0*sbo + w1*cbo
  gemm2_k<64, 1, 1, 4, 0><<<dim3(16, 16, 1), blk, 0, stream>>>(
      attnS, nu, 1024, 0, attnE, 1024, 1024,
      sWob, nu, 1024, 0, cWob, 1024,
      nf, nf, 0, nf,
      rattn, nullptr, 1024, 0,
      2048, ZBIG, 1.f, sbo, cbo, rw, nf);

  // routed = h_lstm + rattn + rattn@Wres^T + bres (+ bf16 mirror) — legacy path
  gemm_k<64, 1, 0, 1, 0><<<dim3(16, 16), blk, 0, stream>>>(
      rattn, 1024, Wresb, 1024, bres,
      routed, routedb, 1024,
      1024, 1.f, hl, rattn);

  // compressed / expanded — legacy path (f32 A)
  gemm_k<64, 0, 0, 1, 0><<<dim3(4, 16), blk, 0, stream>>>(
      ts, 1024, Wcompb, 1024, bcomp,
      comp, nullptr, 256,
      1024, 1.f, nf, nf);
  gemm_k<64, 0, 0, 1, 0><<<dim3(16, 16), blk, 0, stream>>>(
      comp, 256, Wexpb, 256, bexp,
      expd, nullptr, 1024,
      256, 1.f, nf, nf);

  // gate GEMM (A = [xb | routedb]) + fused final epilogue
  gemm2_k<64, 1, 0, 2, 0><<<dim3(16, 16, 1), blk, 0, stream>>>(
      xb, nu, 1024, 0, routedb, 1024, 1024,
      Wgateb, nu, 2048, 0, nu, 0,
      bgate, nf, 0, nf,
      hFinal_out, nullptr, 1024, 0,
      2048, ZBIG, 1.f, comp, expd, hl, routed);
}